// Round 14
// baseline (662.964 us; speedup 1.0000x reference)
//
#include <hip/hip_runtime.h>
#include <math.h>

// SGD filter design: 999 sequential SGD steps on one SOS section (all 16
// provably identical). Round 14: SINGLE WAVE (64 threads), 8 freqs/lane
// as 4 packed <2 x float> pairs. Zero LDS, zero barriers: the full
// 512-freq reduction is packed accumulation + horizontal add + one
// 6-stage DPP tree + 5 readlanes.

typedef float v2 __attribute__((ext_vector_type(2)));

// LR * K * C * 8  (K = 6.020599913279624, C = 0.033929256398692726)
#define LRK8_ 3.2683916458e-5f
// 1/(8K)
#define INVK8_ 0.020762050593046017f

__device__ __forceinline__ float rcp_(float x)  { return __builtin_amdgcn_rcpf(x); }
__device__ __forceinline__ float sqrt_(float x) { return __builtin_amdgcn_sqrtf(x); }
__device__ __forceinline__ float log2_(float x) { return __builtin_amdgcn_logf(x); }
__device__ __forceinline__ float exp2_(float x) { return __builtin_amdgcn_exp2f(x); }

template <int CTRL>
__device__ __forceinline__ float dpp_add(float x) {
    int y = __builtin_amdgcn_update_dpp(0, __float_as_int(x), CTRL, 0xF, 0xF, true);
    return x + __int_as_float(y);
}

// Full 64-lane sum; result valid at lane 63.
__device__ __forceinline__ float wave_sum_at63(float x) {
    x = dpp_add<0x111>(x);  // row_shr:1
    x = dpp_add<0x112>(x);  // row_shr:2
    x = dpp_add<0x114>(x);  // row_shr:4
    x = dpp_add<0x118>(x);  // row_shr:8
    x = dpp_add<0x142>(x);  // row_bcast:15
    x = dpp_add<0x143>(x);  // row_bcast:31
    return x;
}

__device__ __forceinline__ float bcast63(float x) {
    return __int_as_float(__builtin_amdgcn_readlane(__float_as_int(x), 63));
}

__global__ __launch_bounds__(64) void sgd_filter_kernel(const float* __restrict__ tgt,
                                                        float* __restrict__ out) {
    const int lane = threadIdx.x;      // 0..63

    // 8 frequencies per lane: f = lane + 64*j (j=0..7), packed as 4 v2:
    // pair j holds {lane+64j, lane+64j+256}
    v2 C1[4], S1[4], C2[4], S2[4], TK[4];
    #pragma unroll
    for (int j = 0; j < 4; ++j) {
        int f0 = lane + 64 * j;
        int f1 = f0 + 256;
        float wa = (float)(3.14159265358979323846 * (double)f0 / 511.0);
        float wb = (float)(3.14159265358979323846 * (double)f1 / 511.0);
        float sa, ca, sb, cb;
        sincosf(wa, &sa, &ca);
        sincosf(wb, &sb, &cb);
        C1[j] = (v2){ca, cb};
        S1[j] = (v2){sa, sb};
        C2[j] = (v2){ca * ca - sa * sa, cb * cb - sb * sb};
        S2[j] = (v2){2.0f * ca * sa, 2.0f * cb * sb};
        TK[j] = (v2){tgt[f0] * INVK8_, tgt[f1] * INVK8_};
    }

    // lane-replicated parameters, packed {p, z}
    float q0 = 1.0f;
    v2 qr = {1.0f, 1.0f};
    v2 qi = {1.0f, 1.0f};

    for (int it = 0; it < 999; ++it) {
        // ---- uniform forward, packed {p,z} ----
        float g = q0 + 1.0f;
        v2 d2 = qr * qr + qi * qi;
        v2 u  = {sqrt_(d2.x), sqrt_(d2.y)};
        v2 iu = {rcp_(u.x), rcp_(u.y)};
        v2 ea = u * 2.8853900817779268f;            // 2/ln2
        v2 e  = {exp2_(ea.x), exp2_(ea.y)};
        v2 e1 = e + 1.0f;
        v2 re = {rcp_(e1.x), rcp_(e1.y)};
        v2 t  = 1.0f - 2.0f * re;                   // {tanh pu, tanh zu}
        v2 sc = t * iu;
        v2 rs = qr * sc;                            // {prs, zrs}
        v2 is = qi * sc;                            // {pis, zis}

        float zq = t.y * t.y;
        float b0 = g;
        float b1 = -2.0f * g * rs.y;
        float b2 = g * zq;
        float a1 = -2.0f * rs.x;
        float a2 = t.x * t.x;

        // ---- per-frequency forward + adjoint, 4 packed pairs ----
        v2 A0 = {0.0f, 0.0f}, A1 = {0.0f, 0.0f}, A2 = {0.0f, 0.0f};
        v2 A3 = {0.0f, 0.0f}, A4 = {0.0f, 0.0f};
        #pragma unroll
        for (int j = 0; j < 4; ++j) {
            v2 Br = b0 + b1 * C1[j] + b2 * C2[j];
            v2 Bi = -(b1 * S1[j] + b2 * S2[j]);
            v2 Ar = 1.0f + a1 * C1[j] + a2 * C2[j];
            v2 Ai = -(a1 * S1[j] + a2 * S2[j]);
            v2 nb = Br * Br + Bi * Bi;
            v2 na = Ar * Ar + Ai * Ai;
            v2 rnb = {rcp_(nb.x), rcp_(nb.y)};
            v2 rna = {rcp_(na.x), rcp_(na.y)};
            v2 r  = nb * rna;
            v2 lg = {log2_(r.x), log2_(r.y)};
            v2 cF = LRK8_ * (lg - TK[j]);
            v2 cb = cF * rnb;
            v2 ca = cF * rna;
            v2 cbBr = cb * Br, cbBi = cb * Bi;
            v2 caAr = ca * Ar, caAi = ca * Ai;
            A0 += cbBr;
            A1 += cbBr * C1[j] - cbBi * S1[j];
            A2 += cbBr * C2[j] - cbBi * S2[j];
            A3 += caAr * C1[j] - caAi * S1[j];
            A4 += caAr * C2[j] - caAi * S2[j];
        }

        // ---- horizontal + in-wave DPP sums, broadcast via readlane 63 ----
        float S0  = bcast63(wave_sum_at63(A0.x + A0.y));
        float Sb1 = bcast63(wave_sum_at63(A1.x + A1.y));
        float Sb2 = bcast63(wave_sum_at63(A2.x + A2.y));
        float Sa1 = bcast63(wave_sum_at63(-(A3.x + A3.y)));
        float Sa2 = bcast63(wave_sum_at63(-(A4.x + A4.y)));

        // ---- uniform backward, packed {p,z} (LR folded into cF) ----
        float dg = S0 - 2.0f * rs.y * Sb1 + zq * Sb2;
        v2 gg2 = {2.0f, 2.0f * g};
        v2 S42 = {Sa2, Sb2};
        v2 S31 = {Sa1, Sb1};
        v2 dr = gg2 * (rs * S42 - S31);             // {dpr, dzr}
        v2 di = gg2 * (is * S42);                   // {dpi, dzi}
        v2 ds = ((1.0f - t * t) - t * iu) * iu;
        v2 dotv = qr * dr + qi * di;
        v2 com = ds * iu * dotv;
        v2 gqr = sc * dr + qr * com;
        v2 gqi = sc * di + qi * com;

        q0 -= dg;
        qr -= gqr;
        qi -= gqi;
    }

    // ---- final pz_to_sos, 16 identical sections (96 floats, 64 lanes) ----
    {
        float g = q0 + 1.0f;
        v2 d2 = qr * qr + qi * qi;
        v2 u  = {sqrt_(d2.x), sqrt_(d2.y)};
        v2 iu = {rcp_(u.x), rcp_(u.y)};
        v2 ea = u * 2.8853900817779268f;
        v2 e  = {exp2_(ea.x), exp2_(ea.y)};
        v2 e1 = e + 1.0f;
        v2 re = {rcp_(e1.x), rcp_(e1.y)};
        v2 t  = 1.0f - 2.0f * re;
        v2 sc = t * iu;
        v2 rs = qr * sc;
        float b0 = g;
        float b1 = -2.0f * g * rs.y;
        float b2 = g * (t.y * t.y);
        float a1 = -2.0f * rs.x;
        float a2 = t.x * t.x;

        int c = lane % 6;
        float v = (c == 0) ? b0 : (c == 1) ? b1 : (c == 2) ? b2
                : (c == 3) ? 1.0f : (c == 4) ? a1 : a2;
        out[lane] = v;
        if (lane < 32) {
            int c2 = (lane + 64) % 6;
            float v2s = (c2 == 0) ? b0 : (c2 == 1) ? b1 : (c2 == 2) ? b2
                      : (c2 == 3) ? 1.0f : (c2 == 4) ? a1 : a2;
            out[lane + 64] = v2s;
        }
    }
}

extern "C" void kernel_launch(void* const* d_in, const int* in_sizes, int n_in,
                              void* d_out, int out_size, void* d_ws, size_t ws_size,
                              hipStream_t stream) {
    (void)in_sizes; (void)n_in; (void)d_ws; (void)ws_size; (void)out_size;
    const float* tgt = (const float*)d_in[0];
    float* out = (float*)d_out;
    hipLaunchKernelGGL(sgd_filter_kernel, dim3(1), dim3(64), 0, stream, tgt, out);
}

// Round 15
// 453.371 us; speedup vs baseline: 1.4623x; 1.4623x over previous
//
#include <hip/hip_runtime.h>
#include <math.h>

// SGD filter design: 999 sequential SGD steps on one SOS section (all 16
// provably identical). Round 15 = round-13 structure (256 thr = 4 waves,
// 2 freqs/lane packed, DPP reduce, 1 barrier/iter) + trans-op diet:
//  - v_rsq replaces v_sqrt+v_rcp (trans are quarter-rate: the r14 experiment
//    showed 16cy/trans issue dominates; 14 -> 12 trans/iter)
//  - cF via single fma (TKC prefolded), dsiu/g2 hoisted off the post-S tail

typedef float v2 __attribute__((ext_vector_type(2)));

// LR * K * C * 8  (K = 6.020599913279624, C = 0.033929256398692726)
#define LRK8_ 3.2683916458e-5f
// 1/(8K)
#define INVK8_ 0.020762050593046017f

__device__ __forceinline__ float rcp_(float x)  { return __builtin_amdgcn_rcpf(x); }
__device__ __forceinline__ float rsq_(float x)  { return __builtin_amdgcn_rsqf(x); }
__device__ __forceinline__ float log2_(float x) { return __builtin_amdgcn_logf(x); }
__device__ __forceinline__ float exp2_(float x) { return __builtin_amdgcn_exp2f(x); }

template <int CTRL>
__device__ __forceinline__ float dpp_add(float x) {
    int y = __builtin_amdgcn_update_dpp(0, __float_as_int(x), CTRL, 0xF, 0xF, true);
    return x + __int_as_float(y);
}

// Full 64-lane sum; result valid at lane 63.
__device__ __forceinline__ float wave_sum_at63(float x) {
    x = dpp_add<0x111>(x);  // row_shr:1
    x = dpp_add<0x112>(x);  // row_shr:2
    x = dpp_add<0x114>(x);  // row_shr:4
    x = dpp_add<0x118>(x);  // row_shr:8
    x = dpp_add<0x142>(x);  // row_bcast:15
    x = dpp_add<0x143>(x);  // row_bcast:31
    return x;
}

__device__ __forceinline__ float readlane_f(float x, int l) {
    return __int_as_float(__builtin_amdgcn_readlane(__float_as_int(x), l));
}

__global__ __launch_bounds__(256) void sgd_filter_kernel(const float* __restrict__ tgt,
                                                         float* __restrict__ out) {
    const int tid  = threadIdx.x;      // 0..255
    const int lane = tid & 63;
    const int wv   = tid >> 6;         // wave 0..3

    // two frequencies per lane, packed: element0 = tid, element1 = tid+256
    const float wA = (float)(3.14159265358979323846 * (double)tid / 511.0);
    const float wB = (float)(3.14159265358979323846 * (double)(tid + 256) / 511.0);
    float s1a, c1a, s1b, c1b;
    sincosf(wA, &s1a, &c1a);
    sincosf(wB, &s1b, &c1b);
    const v2 C1 = {c1a, c1b};
    const v2 S1 = {s1a, s1b};
    const v2 C2 = {c1a * c1a - s1a * s1a, c1b * c1b - s1b * s1b};
    const v2 S2 = {2.0f * c1a * s1a, 2.0f * c1b * s1b};
    // TKC = LRK8 * tg/(8K): cF = fma(LRK8, lg, -TKC)
    const v2 TKC = {tgt[tid] * (INVK8_ * LRK8_), tgt[tid + 256] * (INVK8_ * LRK8_)};

    // lane-replicated parameters, packed {p, z}
    float q0 = 1.0f;                 // g = q0 + 1
    v2 qr = {1.0f, 1.0f};            // {qpr, qzr}
    v2 qi = {1.0f, 1.0f};            // {qpi, qzi}

    __shared__ float part[2][32];    // [pp][wv*8 + l], l = 0..4

    const int widx = wv << 3;
    const int ridx = (((lane & 3) << 3) | (lane >> 2)) & 31; // lanes 0..19 useful

    for (int it = 0; it < 999; ++it) {
        // ---- uniform forward, packed {p,z} ----
        float g = q0 + 1.0f;
        v2 d2 = qr * qr + qi * qi;
        v2 iu = {rsq_(d2.x), rsq_(d2.y)};           // 1/|.| directly
        v2 u  = d2 * iu;                            // |.| = d2 * rsq(d2)
        v2 ea = u * 2.8853900817779268f;            // 2/ln2
        v2 e  = {exp2_(ea.x), exp2_(ea.y)};
        v2 e1 = e + 1.0f;
        v2 re = {rcp_(e1.x), rcp_(e1.y)};
        v2 t  = 1.0f - 2.0f * re;                   // {tanh pu, tanh zu}
        v2 sc = t * iu;
        v2 rs = qr * sc;                            // {prs, zrs}
        v2 is = qi * sc;                            // {pis, zis}

        float zq = t.y * t.y;                       // zrs^2+zis^2
        float g2 = 2.0f * g;
        float b0 = g;
        float b1 = -g2 * rs.y;
        float b2 = g * zq;
        float a1 = -2.0f * rs.x;
        float a2 = t.x * t.x;

        // hoisted off the post-S tail (depends only on t, iu)
        v2 dsiu = (((1.0f - t * t) - t * iu) * iu) * iu;
        v2 gg2  = {2.0f, g2};

        // ---- per-frequency forward + adjoint, both freqs packed ----
        v2 Br = b0 + b1 * C1 + b2 * C2;
        v2 Bi = -(b1 * S1 + b2 * S2);
        v2 Ar = 1.0f + a1 * C1 + a2 * C2;
        v2 Ai = -(a1 * S1 + a2 * S2);
        v2 nb = Br * Br + Bi * Bi;
        v2 na = Ar * Ar + Ai * Ai;
        v2 rnb = {rcp_(nb.x), rcp_(nb.y)};
        v2 rna = {rcp_(na.x), rcp_(na.y)};
        v2 r  = nb * rna;
        v2 lg = {log2_(r.x), log2_(r.y)};
        v2 cF = LRK8_ * lg - TKC;                   // single packed fma
        v2 cb = cF * rnb;
        v2 ca = cF * rna;
        v2 cbBr = cb * Br, cbBi = cb * Bi;
        v2 caAr = ca * Ar, caAi = ca * Ai;
        v2 gb1v = cbBr * C1 - cbBi * S1;
        v2 gb2v = cbBr * C2 - cbBi * S2;
        v2 ga1v = caAr * C1 - caAi * S1;
        v2 ga2v = caAr * C2 - caAi * S2;

        // ---- horizontal + in-wave DPP sums (valid at lane 63) ----
        float t0 = wave_sum_at63(cbBr.x + cbBr.y);
        float t1 = wave_sum_at63(gb1v.x + gb1v.y);
        float t2 = wave_sum_at63(gb2v.x + gb2v.y);
        float t3 = wave_sum_at63(-(ga1v.x + ga1v.y));
        float t4 = wave_sum_at63(-(ga2v.x + ga2v.y));

        const int pp = it & 1;
        if (lane == 63) {
            float* pb = &part[pp][widx];
            pb[0] = t0; pb[1] = t1; pb[2] = t2; pb[3] = t3; pb[4] = t4;
        }
        __syncthreads();

        // ---- cross-wave: groups of 4 ----
        float y = part[pp][ridx];
        y = dpp_add<0x111>(y);
        y = dpp_add<0x112>(y);
        float S0  = readlane_f(y, 3);
        float Sb1 = readlane_f(y, 7);
        float Sb2 = readlane_f(y, 11);
        float Sa1 = readlane_f(y, 15);
        float Sa2 = readlane_f(y, 19);

        // ---- uniform backward, packed {p,z} (LR folded into cF) ----
        float dg = S0 - 2.0f * rs.y * Sb1 + zq * Sb2;
        v2 S42 = {Sa2, Sb2};
        v2 S31 = {Sa1, Sb1};
        v2 dr = gg2 * (rs * S42 - S31);             // {dpr, dzr}
        v2 di = gg2 * (is * S42);                   // {dpi, dzi}
        v2 dotv = qr * dr + qi * di;
        v2 com = dsiu * dotv;
        v2 gqr = sc * dr + qr * com;
        v2 gqi = sc * di + qi * com;

        q0 -= dg;
        qr -= gqr;
        qi -= gqi;
    }

    // ---- final pz_to_sos, 16 identical sections ----
    {
        float g = q0 + 1.0f;
        v2 d2 = qr * qr + qi * qi;
        v2 iu = {rsq_(d2.x), rsq_(d2.y)};
        v2 u  = d2 * iu;
        v2 ea = u * 2.8853900817779268f;
        v2 e  = {exp2_(ea.x), exp2_(ea.y)};
        v2 e1 = e + 1.0f;
        v2 re = {rcp_(e1.x), rcp_(e1.y)};
        v2 t  = 1.0f - 2.0f * re;
        v2 sc = t * iu;
        v2 rs = qr * sc;
        float b0 = g;
        float b1 = -2.0f * g * rs.y;
        float b2 = g * (t.y * t.y);
        float a1 = -2.0f * rs.x;
        float a2 = t.x * t.x;
        if (tid < 96) {
            int c = tid % 6;
            float v = (c == 0) ? b0 : (c == 1) ? b1 : (c == 2) ? b2
                    : (c == 3) ? 1.0f : (c == 4) ? a1 : a2;
            out[tid] = v;
        }
    }
}

extern "C" void kernel_launch(void* const* d_in, const int* in_sizes, int n_in,
                              void* d_out, int out_size, void* d_ws, size_t ws_size,
                              hipStream_t stream) {
    (void)in_sizes; (void)n_in; (void)d_ws; (void)ws_size; (void)out_size;
    const float* tgt = (const float*)d_in[0];
    float* out = (float*)d_out;
    hipLaunchKernelGGL(sgd_filter_kernel, dim3(1), dim3(256), 0, stream, tgt, out);
}